// Round 4
// baseline (262.981 us; speedup 1.0000x reference)
//
#include <hip/hip_runtime.h>
#include <hip/hip_bf16.h>
#include <stdint.h>

typedef __bf16 bf16_8 __attribute__((ext_vector_type(8)));
typedef float f32x4 __attribute__((ext_vector_type(4)));
typedef unsigned int u32;
typedef unsigned short u16;

// Problem dims (fixed): B=8, R=4, N=1024, D_IN=D_OUT=256.
// Inputs FP32; internal GEMMs bf16 MFMA; output FP32.
// Structure: single-barrier K-loop, B via double-buffered global_load_lds,
// A direct global->register->bf16 (no LDS round trip), K-split x2 for occupancy.

__device__ __forceinline__ u16 f2b(float f) {
    return __builtin_bit_cast(u16, __float2bfloat16(f));
}

// LDS B-tile: 128 rows x 32 k (bf16) as 16B chunks, 4/row, XOR-swizzled so the
// frag reads (fixed g, 16 consecutive rows) stay <=2-way conflicted (free, m136).
__device__ __forceinline__ u32 swz_off(u32 row, u32 g) {
    return (row * 4u + (g ^ ((row >> 1) & 3u))) * 16u;
}

__device__ __forceinline__ void gload_lds16(const void* g, void* l) {
    __builtin_amdgcn_global_load_lds((const __attribute__((address_space(1))) void*)g,
                                     (__attribute__((address_space(3))) void*)l, 16, 0, 0);
}

__device__ __forceinline__ uint4 pack8(float4 a, float4 b) {
    uint4 pk;
    pk.x = (u32)f2b(a.x) | ((u32)f2b(a.y) << 16);
    pk.y = (u32)f2b(a.z) | ((u32)f2b(a.w) << 16);
    pk.z = (u32)f2b(b.x) | ((u32)f2b(b.y) << 16);
    pk.w = (u32)f2b(b.z) | ((u32)f2b(b.w) << 16);
    return pk;
}

// textb = bf16(text), layout preserved [B,N,D_in]. 8 elems/thread.
__global__ __launch_bounds__(256) void text_cvt_kernel(const float* t, u16* tb) {
    const u32 i8 = blockIdx.x * 256u + threadIdx.x;  // 262144 total
    const float4 a = ((const float4*)t)[i8 * 2u];
    const float4 b = ((const float4*)t)[i8 * 2u + 1u];
    ((uint4*)tb)[i8] = pack8(a, b);
}

// Wt[r][dout][din] = bf16(W[r][din][dout])
__global__ __launch_bounds__(256) void wt_cvt_kernel(const float* W, u16* Wt) {
    const u32 idx = blockIdx.x * 256u + threadIdx.x;  // 262144 total
    const u32 r = idx >> 16, rem = idx & 65535u, dout = rem >> 8, din = rem & 255u;
    Wt[idx] = f2b(W[(r << 16) + (din << 8) + dout]);
}

// Yt[b,r,dout,j] = bf16( sum_din Wt[r,dout,din] * textb[b,j,din] )
// Wave tile 32m x 128n; A (Wt) direct from global; B dbuf gload_lds; 1 barrier/iter.
__global__ __launch_bounds__(256, 4) void y_gemm_kernel(const u16* Wt, const u16* textb,
                                                        u16* Yt) {
    __shared__ char smB[16384];
    const u32 bx = blockIdx.x;                 // 512: b(3)|r(2)|m(1)|n(3)
    const u32 n0 = (bx & 7u) * 128u;           // j tile
    const u32 m0 = ((bx >> 3) & 1u) * 128u;    // dout tile
    const u32 r  = (bx >> 4) & 3u;
    const u32 b  = bx >> 6;
    const u16* pA = Wt + (size_t)r * 65536u + (size_t)m0 * 256u;
    const u16* pB = textb + (size_t)b * 262144u + (size_t)n0 * 256u;

    const u32 t = threadIdx.x, lane = t & 63u, w = t >> 6;
    const u32 wm = w * 32u;
    const u32 waveByte = (t & 192u) * 16u;
    const u32 row0 = t >> 2;
    const u32 gg0  = (t & 3u) ^ ((row0 >> 1) & 3u);
    const u32 row1 = row0 + 64u;
    const u32 gg1  = ((t + 256u) & 3u) ^ ((row1 >> 1) & 3u);
    const u32 fr = lane & 15u, fg = lane >> 4;

    f32x4 acc[2][8];
#pragma unroll
    for (int i = 0; i < 2; ++i)
#pragma unroll
        for (int j = 0; j < 8; ++j) acc[i][j] = (f32x4){0.f, 0.f, 0.f, 0.f};

    const u16* ap0 = pA + (size_t)(wm + fr) * 256u + fg * 8u;        // mt=0 row
    const u16* ap1 = ap0 + 16u * 256u;                               // mt=1 row

    gload_lds16(pB + (size_t)row0 * 256u + gg0 * 8u, smB + waveByte);
    gload_lds16(pB + (size_t)row1 * 256u + gg1 * 8u, smB + waveByte + 4096u);
    uint4 a0 = *(const uint4*)ap0;
    uint4 a1 = *(const uint4*)ap1;

    for (int ks = 0; ks < 8; ++ks) {
        __syncthreads();  // drains B(ks) + A(ks) (issued one full iter ago)
        bf16_8 af0 = __builtin_bit_cast(bf16_8, a0);
        bf16_8 af1 = __builtin_bit_cast(bf16_8, a1);
        const u32 kn = (ks < 7) ? (u32)(ks + 1) * 32u : 0u;
        const u32 nb = (((u32)ks + 1u) & 1u) * 8192u;
        gload_lds16(pB + (size_t)row0 * 256u + kn + gg0 * 8u, smB + nb + waveByte);
        gload_lds16(pB + (size_t)row1 * 256u + kn + gg1 * 8u, smB + nb + waveByte + 4096u);
        a0 = *(const uint4*)(ap0 + kn);
        a1 = *(const uint4*)(ap1 + kn);
        char* rb = smB + ((u32)ks & 1u) * 8192u;
#pragma unroll
        for (int nt = 0; nt < 8; ++nt) {
            uint4 v = *(const uint4*)(rb + swz_off((u32)nt * 16u + fr, fg));
            bf16_8 bf = __builtin_bit_cast(bf16_8, v);
            acc[0][nt] = __builtin_amdgcn_mfma_f32_16x16x32_bf16(af0, bf, acc[0][nt], 0, 0, 0);
            acc[1][nt] = __builtin_amdgcn_mfma_f32_16x16x32_bf16(af1, bf, acc[1][nt], 0, 0, 0);
        }
    }

    const u32 rit = (lane >> 4) * 4u, cit = lane & 15u;  // C: row=(lane>>4)*4+reg
    u16* yb = Yt + (size_t)(b * 4u + r) * 262144u;
#pragma unroll
    for (int mt = 0; mt < 2; ++mt)
#pragma unroll
        for (int nt = 0; nt < 8; ++nt) {
            const u32 m = m0 + wm + (u32)mt * 16u + rit;
            const u32 n = n0 + (u32)nt * 16u + cit;
#pragma unroll
            for (int rg = 0; rg < 4; ++rg)
                yb[(size_t)(m + (u32)rg) * 1024u + n] = f2b(acc[mt][nt][rg]);
        }
}

// partial[b,r,kh,i,d] = sum_{j in k-half} adj[b,r,i,j]*Yt[b,r,d,j]  (UNnormalized)
// rsum[b,r,kh,i]     = sum_{j in k-half} adj[b,r,i,j]  (fp32, pre-quantization)
// Normalization (1/rowsum) is linear -> applied in reduce_kernel.
__global__ __launch_bounds__(256, 4) void adj_gemm_fused(const float* adj, const u16* Yt,
                                                         float* partial, float* rsum) {
    __shared__ char smB[16384];
    const u32 bx = blockIdx.x;                 // 1024: b(3)|r(2)|kh(1)|n(1)|i(3)
    const u32 m0 = (bx & 7u) * 128u;           // i tile (low bits: n-siblings share XCD)
    const u32 n0 = ((bx >> 3) & 1u) * 128u;    // dout tile
    const u32 kh = (bx >> 4) & 1u;             // k half
    const u32 r  = (bx >> 5) & 3u;
    const u32 b  = bx >> 7;
    const u32 br = b * 4u + r;

    const float* pA = adj + (size_t)br * 1048576u + (size_t)m0 * 1024u + kh * 512u;
    const u16*   pB = Yt + (size_t)br * 262144u + (size_t)n0 * 1024u + kh * 512u;

    const u32 t = threadIdx.x, lane = t & 63u, w = t >> 6;
    const u32 wm = w * 32u;                    // wave tile 32m x 128n, no row overlap
    const u32 waveByte = (t & 192u) * 16u;
    const u32 row0 = t >> 2;
    const u32 gg0  = (t & 3u) ^ ((row0 >> 1) & 3u);
    const u32 row1 = row0 + 64u;
    const u32 gg1  = ((t + 256u) & 3u) ^ ((row1 >> 1) & 3u);
    const u32 fr = lane & 15u, fg = lane >> 4;

    f32x4 acc[2][8];
#pragma unroll
    for (int i = 0; i < 2; ++i)
#pragma unroll
        for (int j = 0; j < 8; ++j) acc[i][j] = (f32x4){0.f, 0.f, 0.f, 0.f};

    const float* ap0 = pA + (size_t)(wm + fr) * 1024u + fg * 8u;
    const float* ap1 = ap0 + 16u * 1024u;

    gload_lds16(pB + (size_t)row0 * 1024u + gg0 * 8u, smB + waveByte);
    gload_lds16(pB + (size_t)row1 * 1024u + gg1 * 8u, smB + waveByte + 4096u);
    float4 a0 = *(const float4*)(ap0);
    float4 a1 = *(const float4*)(ap0 + 4);
    float4 a2 = *(const float4*)(ap1);
    float4 a3 = *(const float4*)(ap1 + 4);
    float s0 = 0.f, s1 = 0.f;

    for (int ks = 0; ks < 16; ++ks) {
        __syncthreads();  // drains B(ks) gload_lds + A(ks) reg loads (1 iter in flight)
        bf16_8 af0 = __builtin_bit_cast(bf16_8, pack8(a0, a1));
        bf16_8 af1 = __builtin_bit_cast(bf16_8, pack8(a2, a3));
        s0 += (a0.x + a0.y + a0.z + a0.w) + (a1.x + a1.y + a1.z + a1.w);
        s1 += (a2.x + a2.y + a2.z + a2.w) + (a3.x + a3.y + a3.z + a3.w);
        const u32 kn = (ks < 15) ? (u32)(ks + 1) * 32u : 0u;
        const u32 nb = (((u32)ks + 1u) & 1u) * 8192u;
        gload_lds16(pB + (size_t)row0 * 1024u + kn + gg0 * 8u, smB + nb + waveByte);
        gload_lds16(pB + (size_t)row1 * 1024u + kn + gg1 * 8u, smB + nb + waveByte + 4096u);
        a0 = *(const float4*)(ap0 + kn);
        a1 = *(const float4*)(ap0 + kn + 4);
        a2 = *(const float4*)(ap1 + kn);
        a3 = *(const float4*)(ap1 + kn + 4);
        char* rb = smB + ((u32)ks & 1u) * 8192u;
#pragma unroll
        for (int nt = 0; nt < 8; ++nt) {
            uint4 v = *(const uint4*)(rb + swz_off((u32)nt * 16u + fr, fg));
            bf16_8 bf = __builtin_bit_cast(bf16_8, v);
            acc[0][nt] = __builtin_amdgcn_mfma_f32_16x16x32_bf16(af0, bf, acc[0][nt], 0, 0, 0);
            acc[1][nt] = __builtin_amdgcn_mfma_f32_16x16x32_bf16(af1, bf, acc[1][nt], 0, 0, 0);
        }
    }

    // Row sums: lanes {fr, fr+16, fr+32, fr+48} hold the fg-partials of one row.
    s0 += __shfl_down(s0, 32, 64); s0 += __shfl_down(s0, 16, 64);
    s1 += __shfl_down(s1, 32, 64); s1 += __shfl_down(s1, 16, 64);
    float* rsp = rsum + (size_t)(br * 2u + kh) * 1024u + m0 + wm;
    if (lane < 16u) {               // n-split sibling writes identical bits: benign
        rsp[lane] = s0;
        rsp[16u + lane] = s1;
    }

    const u32 rit = (lane >> 4) * 4u, cit = lane & 15u;
    float* pp = partial + (size_t)(br * 2u + kh) * 262144u;
#pragma unroll
    for (int mt = 0; mt < 2; ++mt) {
        const u32 mB = m0 + wm + (u32)mt * 16u + rit;
#pragma unroll
        for (int nt = 0; nt < 8; ++nt) {
            const u32 n = n0 + (u32)nt * 16u + cit;
#pragma unroll
            for (int rg = 0; rg < 4; ++rg)
                pp[(size_t)(mB + (u32)rg) * 256u + n] = acc[mt][nt][rg];
        }
    }
}

// out[b,i,d] = bias[d] + sum_r inv[b,r,i] * (partial[b,r,0,i,d]+partial[b,r,1,i,d])
__global__ __launch_bounds__(256) void reduce_kernel(const float* partial, const float* rsum,
                                                     const float* bias, float* out) {
    const u32 i4 = blockIdx.x * 256u + threadIdx.x;  // 524288 threads, 4 f32 each
    const u32 base = i4 * 4u;
    const u32 b = base >> 18;
    const u32 rem = base & 262143u;
    const u32 i = rem >> 8;
    float4 s = ((const float4*)bias)[i4 & 63u];
#pragma unroll
    for (u32 r = 0; r < 4; ++r) {
        const u32 brk = (b * 4u + r) * 2u;
        const float rs = rsum[(size_t)brk * 1024u + i] + rsum[(size_t)(brk + 1u) * 1024u + i];
        const float inv = (rs == 0.f) ? 0.f : 1.f / rs;
        const float4 p0 = *(const float4*)(partial + ((size_t)brk << 18) + rem);
        const float4 p1 = *(const float4*)(partial + ((size_t)(brk + 1u) << 18) + rem);
        s.x += inv * (p0.x + p1.x);
        s.y += inv * (p0.y + p1.y);
        s.z += inv * (p0.z + p1.z);
        s.w += inv * (p0.w + p1.w);
    }
    ((float4*)out)[i4] = s;
}

extern "C" void kernel_launch(void* const* d_in, const int* in_sizes, int n_in,
                              void* d_out, int out_size, void* d_ws, size_t ws_size,
                              hipStream_t stream) {
    const float* text = (const float*)d_in[0];  // [8,1024,256] fp32
    const float* adj  = (const float*)d_in[1];  // [8,4,1024,1024] fp32
    const float* wgt  = (const float*)d_in[2];  // [4,256,256] fp32
    const float* bias = (const float*)d_in[3];  // [256] fp32
    float* out = (float*)d_out;                 // [8,1024,256] fp32

    char* ws = (char*)d_ws;
    u16* Yt        = (u16*)ws;                      // 16 MB  bf16 [B,R,256,1024]
    u16* textb     = (u16*)(ws + 16777216u);        //  4 MB  bf16 [B,N,256]
    u16* Wt        = (u16*)(ws + 20971520u);        // 512 KB bf16 [R,256,256]
    float* partial = (float*)(ws + 21495808u);      // 64 MB  fp32 [B,R,2,N,256]
    float* rsum    = (float*)(ws + 88604672u);      // 256 KB fp32 [B,R,2,N]

    text_cvt_kernel<<<1024, 256, 0, stream>>>(text, textb);
    wt_cvt_kernel<<<1024, 256, 0, stream>>>(wgt, Wt);
    y_gemm_kernel<<<512, 256, 0, stream>>>(Wt, textb, Yt);
    adj_gemm_fused<<<1024, 256, 0, stream>>>(adj, Yt, partial, rsum);
    reduce_kernel<<<2048, 256, 0, stream>>>(partial, rsum, bias, out);
}